// Round 13
// baseline (93.229 us; speedup 1.0000x reference)
//
#include <hip/hip_runtime.h>
#include <cmath>
#include <cstdint>

#pragma clang fp contract(off)

typedef unsigned long long ull;

constexpr float POS_THR = 0.5f;
constexpr float NEG_THR = 0.4f;
constexpr float F32_EPS = 1.1920928955078125e-07f;  // jnp.finfo(float32).eps

// Contraction-proof area: one rounding per op, identical in every kernel.
__device__ __forceinline__ float area_of(const float4 b) {
    return __fmul_rn(__fsub_rn(b.z, b.x), __fsub_rn(b.w, b.y));
}

__device__ __forceinline__ float iou_one(const float4 a, const float area_a,
                                         const float4 g, const float area_g) {
    // EXACT per-op rounding (matches numpy reference; no fma contraction
    // anywhere -> bit-identical across kernels and inline contexts).
    float lx = fmaxf(a.x, g.x);
    float ly = fmaxf(a.y, g.y);
    float rx = fminf(a.z, g.z);
    float ry = fminf(a.w, g.w);
    float w  = fmaxf(__fsub_rn(rx, lx), 0.0f);
    float h  = fmaxf(__fsub_rn(ry, ly), 0.0f);
    float inter = __fmul_rn(w, h);
    float denom = __fsub_rn(__fadd_rn(area_a, area_g), inter);
    return __fdiv_rn(inter, denom);
}

__device__ __forceinline__ float4 encode_box(const float4 a, const float4 g) {
    float ax = (a.x + a.z) * 0.5f;
    float ay = (a.y + a.w) * 0.5f;
    float aw = fmaxf(a.z - a.x, F32_EPS);
    float ah = fmaxf(a.w - a.y, F32_EPS);
    float gx = (g.x + g.z) * 0.5f;
    float gy = (g.y + g.w) * 0.5f;
    float gw = g.z - g.x;
    float gh = g.w - g.y;
    return make_float4((gx - ax) / aw, (gy - ay) / ah, logf(gw / aw), logf(gh / ah));
}

__device__ __forceinline__ ull shfl_xor_u64(ull key, int off) {
    unsigned lo = (unsigned)key;
    unsigned hi = (unsigned)(key >> 32);
    lo = __shfl_xor(lo, off, 64);
    hi = __shfl_xor(hi, off, 64);
    return ((ull)hi << 32) | lo;
}

// One block = 128-anchor x 128-gt tile; 16x16 threads, 8x8 subtile each.
// Each unique IoU computed EXACTLY ONCE. Row argmax: value+local-idx chains.
// Col argmax: VALUE-ONLY fmax chains in the hot loop (index recovered in
// reduce_fixup by bit-identical recompute of the winning block).
// Merge buffers u32 [128][17]: odd dword stride -> <=2-way banks (free).
__global__ __launch_bounds__(256, 4) void fused_kernel(
    const float4* __restrict__ anchors, const float4* __restrict__ gts,
    const int* __restrict__ labels, int n, int m, int nblocks,
    float* __restrict__ out_cls, float4* __restrict__ out_reg,
    float* __restrict__ out_pos, ull* __restrict__ ws)
{
    __shared__ float4   sA[128];
    __shared__ unsigned sKv[128][17];   // value bits (row phase, then col values)
    __shared__ unsigned sKi[128][17];   // ~local col index (row phase only)

    const int t = threadIdx.x;
    const int base = blockIdx.x * 128;

    // Stage anchors (tail padded zero-area -> IoU exactly +0).
    if (t < 128) {
        int i = base + t;
        float4 a = make_float4(0.0f, 0.0f, 0.0f, 0.0f);
        if (i < n) a = anchors[i];
        sA[t] = a;
    }

    const int tx = t & 15;              // gt-strip
    const int ty = t >> 4;              // anchor-strip
    const int g0 = tx * 8;
    const int a0 = ty * 8;

    // gt strip to registers (2 KB hot, L2-resident, broadcast across ty).
    float4 g[8];
    float  ga[8];
    #pragma unroll
    for (int j = 0; j < 8; ++j) {
        g[j]  = gts[g0 + j];
        ga[j] = area_of(g[j]);
    }

    float cbest[8];
    #pragma unroll
    for (int j = 0; j < 8; ++j) cbest[j] = -1.0f;

    __syncthreads();

    // ---- 8x8 subtile: ai-pairs x unrolled j; one IoU per unique pair ----
    #pragma unroll
    for (int ap = 0; ap < 4; ++ap) {
        const int ai0 = 2 * ap, ai1 = 2 * ap + 1;
        float4 aA = sA[a0 + ai0];
        float4 aB = sA[a0 + ai1];
        float aaA = area_of(aA);
        float aaB = area_of(aB);
        float rbA = -1.0f, rbB = -1.0f;
        int   rjA = 0,     rjB = 0;
        #pragma unroll
        for (int j = 0; j < 8; ++j) {
            float v0 = iou_one(aA, aaA, g[j], ga[j]);
            float v1 = iou_one(aB, aaB, g[j], ga[j]);
            if (v0 > rbA) { rbA = v0; rjA = j; }          // first-max in j
            if (v1 > rbB) { rbB = v1; rjB = j; }
            cbest[j] = fmaxf(cbest[j], fmaxf(v0, v1));    // value only
        }
        sKv[a0 + ai0][tx] = __float_as_uint(rbA);
        sKi[a0 + ai0][tx] = ~(unsigned)(g0 + rjA);
        sKv[a0 + ai1][tx] = __float_as_uint(rbB);
        sKi[a0 + ai1][tx] = ~(unsigned)(g0 + rjB);
    }
    __syncthreads();

    // ---- Row merge + outputs: thread t<128 owns anchor t ----
    if (t < 128) {
        unsigned bv = sKv[t][0];
        unsigned bi = sKi[t][0];
        #pragma unroll
        for (int x = 1; x < 16; ++x) {
            unsigned v = sKv[t][x], i2 = sKi[t][x];
            // larger value wins; equal value -> larger ~idx = smaller idx
            if (v > bv || (v == bv && i2 > bi)) { bv = v; bi = i2; }
        }
        int i = base + t;
        if (i < n) {
            float best = __uint_as_float(bv);
            int bestj  = (int)(~bi);
            bool pos = best >= POS_THR;
            bool neg = (best < NEG_THR) && !pos;
            out_cls[i] = pos ? (float)labels[bestj] : (neg ? 0.0f : -1.0f);
            out_pos[i] = pos ? 1.0f : 0.0f;
            float4 enc = make_float4(0.0f, 0.0f, 0.0f, 0.0f);
            if (pos) enc = encode_box(sA[t], gts[bestj]);
            out_reg[i] = enc;
        }
    }
    __syncthreads();                    // sKv reused for col values

    // ---- Col partials: value only ----
    #pragma unroll
    for (int j = 0; j < 8; ++j)
        sKv[g0 + j][ty] = __float_as_uint(cbest[j]);   // cbest >= 0 always
    __syncthreads();

    // ---- Col merge: unsigned max == float max for non-negative floats ----
    if (t < 128) {
        unsigned bv = sKv[t][0];
        #pragma unroll
        for (int y = 1; y < 16; ++y) { unsigned v = sKv[t][y]; if (v > bv) bv = v; }
        // key: (value_bits<<32) | ~block  -> max = max value, tie -> min block
        ws[(size_t)t * nblocks + blockIdx.x] =
            ((ull)bv << 32) | (ull)(~(unsigned)blockIdx.x);
    }
}

// One 128-thread block per gt:
//  A) max-reduce per-block keys -> first block B achieving the global max
//  B) recompute block B's 128 IoUs (bit-identical: strict per-op rounding)
//     -> first-index argmax within B == global first-index argmax (jax's)
//  C) row argmax for that anchor (bit-identical) -> force-positive outputs.
// Duplicate winners across gts write identical values -> benign race.
__global__ __launch_bounds__(128) void reduce_fixup(
    const float4* __restrict__ anchors, const float4* __restrict__ gts,
    const int* __restrict__ labels, int n, int m, int nblocks,
    float* __restrict__ out_cls, float4* __restrict__ out_reg,
    float* __restrict__ out_pos, const ull* __restrict__ ws)
{
    __shared__ ull redu[2];
    __shared__ ull s_akey;
    __shared__ ull s_bkey;
    __shared__ ull s_ckey;

    const int j = blockIdx.x;
    const int t = threadIdx.x;
    const ull* wj = ws + (size_t)j * nblocks;

    // ---- Phase A: winning block (max value, tie -> min block) ----
    ull key = 0ull;
    for (int b = t; b < nblocks; b += 128) { ull k = wj[b]; if (k > key) key = k; }
    #pragma unroll
    for (int off = 32; off > 0; off >>= 1) {
        ull o = shfl_xor_u64(key, off);
        if (o > key) key = o;
    }
    if ((t & 63) == 0) redu[t >> 6] = key;
    __syncthreads();
    if (t == 0) s_akey = redu[0] > redu[1] ? redu[0] : redu[1];
    __syncthreads();
    const unsigned B = ~(unsigned)s_akey;     // winning block

    // ---- Phase B: first-index argmax within block B (recompute) ----
    float4 gj = gts[j];
    float gaj = area_of(gj);
    {
        int i = (int)B * 128 + t;
        float4 a = make_float4(0.0f, 0.0f, 0.0f, 0.0f);
        if (i < n) a = anchors[i];            // same padding as fused_kernel
        float aa = area_of(a);
        float v = iou_one(a, aa, gj, gaj);
        ull kb = ((ull)__float_as_uint(v) << 32) | (ull)(~(unsigned)t);
        #pragma unroll
        for (int off = 32; off > 0; off >>= 1) {
            ull o = shfl_xor_u64(kb, off);
            if (o > kb) kb = o;
        }
        __syncthreads();                      // redu reuse
        if ((t & 63) == 0) redu[t >> 6] = kb;
    }
    __syncthreads();
    if (t == 0) s_bkey = redu[0] > redu[1] ? redu[0] : redu[1];
    __syncthreads();
    const int giW = (int)B * 128 + (int)(~(unsigned)s_bkey);

    // ---- Phase C: row argmax of anchor giW over all gts ----
    float4 aw = anchors[giW];
    float aaw = area_of(aw);
    ull k2 = 0ull;
    if (t < m) {
        float4 gt_t = gts[t];
        float gat = area_of(gt_t);
        float v2 = iou_one(aw, aaw, gt_t, gat);
        k2 = ((ull)__float_as_uint(v2) << 32) | (ull)(~(unsigned)t);
    }
    #pragma unroll
    for (int off = 32; off > 0; off >>= 1) {
        ull o = shfl_xor_u64(k2, off);
        if (o > k2) k2 = o;
    }
    __syncthreads();                          // redu reuse
    if ((t & 63) == 0) redu[t >> 6] = k2;
    __syncthreads();
    if (t == 0) {
        s_ckey = redu[0] > redu[1] ? redu[0] : redu[1];
        int bj = (int)(~(unsigned)s_ckey);
        out_pos[giW] = 1.0f;
        out_cls[giW] = (float)labels[bj];
        out_reg[giW] = encode_box(aw, gts[bj]);
    }
}

extern "C" void kernel_launch(void* const* d_in, const int* in_sizes, int n_in,
                              void* d_out, int out_size, void* d_ws, size_t ws_size,
                              hipStream_t stream)
{
    const float4* anchors = (const float4*)d_in[0];
    const float4* gts     = (const float4*)d_in[1];
    const int*    labels  = (const int*)d_in[2];
    int n = in_sizes[0] / 4;   // 200000
    int m = in_sizes[1] / 4;   // 128

    float*  out     = (float*)d_out;
    float*  out_cls = out;                       // [n]
    float4* out_reg = (float4*)(out + n);        // [n][4]
    float*  out_pos = out + 5 * (size_t)n;       // [n]
    ull*    ws      = (ull*)d_ws;                // [m][nblocks] packed (val, ~block)

    int nblocks = (n + 127) / 128;               // 1563
    fused_kernel<<<nblocks, 256, 0, stream>>>(anchors, gts, labels, n, m, nblocks,
                                              out_cls, out_reg, out_pos, ws);
    reduce_fixup<<<m, 128, 0, stream>>>(anchors, gts, labels, n, m, nblocks,
                                        out_cls, out_reg, out_pos, ws);
}

// Round 15
// 92.940 us; speedup vs baseline: 1.0031x; 1.0031x over previous
//
#include <hip/hip_runtime.h>
#include <cmath>
#include <cstdint>

#pragma clang fp contract(off)

typedef unsigned long long ull;

constexpr float POS_THR = 0.5f;
constexpr float NEG_THR = 0.4f;
constexpr float F32_EPS = 1.1920928955078125e-07f;  // jnp.finfo(float32).eps

// Contraction-proof area: one rounding per op, identical in every kernel.
__device__ __forceinline__ float area_of(const float4 b) {
    return __fmul_rn(__fsub_rn(b.z, b.x), __fsub_rn(b.w, b.y));
}

__device__ __forceinline__ float iou_one(const float4 a, const float area_a,
                                         const float4 g, const float area_g) {
    // EXACT per-op rounding (matches numpy reference; no fma contraction
    // anywhere -> bit-identical across kernels and inline contexts).
    float lx = fmaxf(a.x, g.x);
    float ly = fmaxf(a.y, g.y);
    float rx = fminf(a.z, g.z);
    float ry = fminf(a.w, g.w);
    float w  = fmaxf(__fsub_rn(rx, lx), 0.0f);
    float h  = fmaxf(__fsub_rn(ry, ly), 0.0f);
    float inter = __fmul_rn(w, h);
    float denom = __fsub_rn(__fadd_rn(area_a, area_g), inter);
    return __fdiv_rn(inter, denom);
}

__device__ __forceinline__ float4 encode_box(const float4 a, const float4 g) {
    float ax = (a.x + a.z) * 0.5f;
    float ay = (a.y + a.w) * 0.5f;
    float aw = fmaxf(a.z - a.x, F32_EPS);
    float ah = fmaxf(a.w - a.y, F32_EPS);
    float gx = (g.x + g.z) * 0.5f;
    float gy = (g.y + g.w) * 0.5f;
    float gw = g.z - g.x;
    float gh = g.w - g.y;
    return make_float4((gx - ax) / aw, (gy - ay) / ah, logf(gw / aw), logf(gh / ah));
}

__device__ __forceinline__ ull shfl_xor_u64(ull key, int off) {
    unsigned lo = (unsigned)key;
    unsigned hi = (unsigned)(key >> 32);
    lo = __shfl_xor(lo, off, 64);
    hi = __shfl_xor(hi, off, 64);
    return ((ull)hi << 32) | lo;
}

// One block = 128-anchor x 128-gt tile; 16x16 threads, 8x8 subtile each.
// TWO barriers total:
//   stage -> bar1 -> compute (+ row-key & col-value LDS writes) -> bar2 ->
//   { threads 0-127: row merge + outputs  ||  threads 128-255: col merge }.
// Output global stores drain at kernel end, never at a barrier.
// Each unique IoU computed EXACTLY ONCE; col chains value-only (index
// recovered in reduce_fixup by bit-identical recompute).
__global__ __launch_bounds__(256, 4) void fused_kernel(
    const float4* __restrict__ anchors, const float4* __restrict__ gts,
    const int* __restrict__ labels, int n, int m, int nblocks,
    float* __restrict__ out_cls, float4* __restrict__ out_reg,
    float* __restrict__ out_pos, ull* __restrict__ ws)
{
    __shared__ float4         sA[128];
    __shared__ unsigned       sKv[128][17];   // row best value bits
    __shared__ unsigned short sKi[128][17];   // row best local gt idx (0..127)
    __shared__ unsigned       sCv[128][17];   // col value partials

    const int t = threadIdx.x;
    const int base = blockIdx.x * 128;

    // Stage anchors (tail padded zero-area -> IoU exactly +0).
    if (t < 128) {
        int i = base + t;
        float4 a = make_float4(0.0f, 0.0f, 0.0f, 0.0f);
        if (i < n) a = anchors[i];
        sA[t] = a;
    }

    const int tx = t & 15;              // gt-strip
    const int ty = t >> 4;              // anchor-strip
    const int g0 = tx * 8;
    const int a0 = ty * 8;

    // gt strip to registers (2 KB hot, L1/L2-resident, shared across ty).
    float4 g[8];
    float  ga[8];
    #pragma unroll
    for (int j = 0; j < 8; ++j) {
        g[j]  = gts[g0 + j];
        ga[j] = area_of(g[j]);
    }

    float cbest[8];
    #pragma unroll
    for (int j = 0; j < 8; ++j) cbest[j] = -1.0f;

    __syncthreads();                    // ---- barrier 1: sA ready ----

    // ---- 8x8 subtile: ai-pairs x unrolled j; one IoU per unique pair ----
    #pragma unroll
    for (int ap = 0; ap < 4; ++ap) {
        const int ai0 = 2 * ap, ai1 = 2 * ap + 1;
        float4 aA = sA[a0 + ai0];
        float4 aB = sA[a0 + ai1];
        float aaA = area_of(aA);
        float aaB = area_of(aB);
        float rbA = -1.0f, rbB = -1.0f;
        int   rjA = 0,     rjB = 0;
        #pragma unroll
        for (int j = 0; j < 8; ++j) {
            float v0 = iou_one(aA, aaA, g[j], ga[j]);
            float v1 = iou_one(aB, aaB, g[j], ga[j]);
            if (v0 > rbA) { rbA = v0; rjA = j; }          // first-max in j
            if (v1 > rbB) { rbB = v1; rjB = j; }
            cbest[j] = fmaxf(cbest[j], fmaxf(v0, v1));    // value only
        }
        sKv[a0 + ai0][tx] = __float_as_uint(rbA);
        sKi[a0 + ai0][tx] = (unsigned short)(g0 + rjA);
        sKv[a0 + ai1][tx] = __float_as_uint(rbB);
        sKi[a0 + ai1][tx] = (unsigned short)(g0 + rjB);
    }
    // Col partials straight from registers (same phase; sCv not yet read).
    #pragma unroll
    for (int j = 0; j < 8; ++j)
        sCv[g0 + j][ty] = __float_as_uint(cbest[j]);      // cbest >= 0 always

    __syncthreads();                    // ---- barrier 2: all partials ready ----

    if (t < 128) {
        // ---- Row merge + outputs: thread t owns anchor t ----
        unsigned bv = sKv[t][0];
        unsigned bi = sKi[t][0];
        #pragma unroll
        for (int x = 1; x < 16; ++x) {
            unsigned v  = sKv[t][x];
            unsigned ii = sKi[t][x];
            // larger value wins; equal value -> smaller gt index
            if (v > bv || (v == bv && ii < bi)) { bv = v; bi = ii; }
        }
        int i = base + t;
        if (i < n) {
            float best = __uint_as_float(bv);
            int bestj  = (int)bi;
            bool pos = best >= POS_THR;
            bool neg = (best < NEG_THR) && !pos;
            out_cls[i] = pos ? (float)labels[bestj] : (neg ? 0.0f : -1.0f);
            out_pos[i] = pos ? 1.0f : 0.0f;
            float4 enc = make_float4(0.0f, 0.0f, 0.0f, 0.0f);
            if (pos) enc = encode_box(sA[t], gts[bestj]);
            out_reg[i] = enc;
        }
    } else {
        // ---- Col merge: thread owns gt (t-128) ----
        int j = t - 128;                 // m == 128
        unsigned bv = sCv[j][0];
        #pragma unroll
        for (int y = 1; y < 16; ++y) { unsigned v = sCv[j][y]; if (v > bv) bv = v; }
        // key: (value_bits<<32) | ~block  -> max = max value, tie -> min block
        ws[(size_t)j * nblocks + blockIdx.x] =
            ((ull)bv << 32) | (ull)(~(unsigned)blockIdx.x);
    }
}

// One 128-thread block per gt:
//  A) max-reduce per-block keys -> first block B achieving the global max
//  B) recompute block B's 128 IoUs (bit-identical: strict per-op rounding)
//     -> first-index argmax within B == global first-index argmax (jax's)
//  C) row argmax for that anchor (bit-identical) -> force-positive outputs.
// Duplicate winners across gts write identical values -> benign race.
__global__ __launch_bounds__(128) void reduce_fixup(
    const float4* __restrict__ anchors, const float4* __restrict__ gts,
    const int* __restrict__ labels, int n, int m, int nblocks,
    float* __restrict__ out_cls, float4* __restrict__ out_reg,
    float* __restrict__ out_pos, const ull* __restrict__ ws)
{
    __shared__ ull redu[2];
    __shared__ ull s_akey;
    __shared__ ull s_bkey;
    __shared__ ull s_ckey;

    const int j = blockIdx.x;
    const int t = threadIdx.x;
    const ull* wj = ws + (size_t)j * nblocks;

    // ---- Phase A: winning block (max value, tie -> min block) ----
    ull key = 0ull;
    for (int b = t; b < nblocks; b += 128) { ull k = wj[b]; if (k > key) key = k; }
    #pragma unroll
    for (int off = 32; off > 0; off >>= 1) {
        ull o = shfl_xor_u64(key, off);
        if (o > key) key = o;
    }
    if ((t & 63) == 0) redu[t >> 6] = key;
    __syncthreads();
    if (t == 0) s_akey = redu[0] > redu[1] ? redu[0] : redu[1];
    __syncthreads();
    const unsigned B = ~(unsigned)s_akey;     // winning block

    // ---- Phase B: first-index argmax within block B (recompute) ----
    float4 gj = gts[j];
    float gaj = area_of(gj);
    {
        int i = (int)B * 128 + t;
        float4 a = make_float4(0.0f, 0.0f, 0.0f, 0.0f);
        if (i < n) a = anchors[i];            // same padding as fused_kernel
        float aa = area_of(a);
        float v = iou_one(a, aa, gj, gaj);
        ull kb = ((ull)__float_as_uint(v) << 32) | (ull)(~(unsigned)t);
        #pragma unroll
        for (int off = 32; off > 0; off >>= 1) {
            ull o = shfl_xor_u64(kb, off);
            if (o > kb) kb = o;
        }
        __syncthreads();                      // redu reuse
        if ((t & 63) == 0) redu[t >> 6] = kb;
    }
    __syncthreads();
    if (t == 0) s_bkey = redu[0] > redu[1] ? redu[0] : redu[1];
    __syncthreads();
    const int giW = (int)B * 128 + (int)(~(unsigned)s_bkey);

    // ---- Phase C: row argmax of anchor giW over all gts ----
    float4 aw = anchors[giW];
    float aaw = area_of(aw);
    ull k2 = 0ull;
    if (t < m) {
        float4 gt_t = gts[t];
        float gat = area_of(gt_t);
        float v2 = iou_one(aw, aaw, gt_t, gat);
        k2 = ((ull)__float_as_uint(v2) << 32) | (ull)(~(unsigned)t);
    }
    #pragma unroll
    for (int off = 32; off > 0; off >>= 1) {
        ull o = shfl_xor_u64(k2, off);
        if (o > k2) k2 = o;
    }
    __syncthreads();                          // redu reuse
    if ((t & 63) == 0) redu[t >> 6] = k2;
    __syncthreads();
    if (t == 0) {
        s_ckey = redu[0] > redu[1] ? redu[0] : redu[1];
        int bj = (int)(~(unsigned)s_ckey);
        out_pos[giW] = 1.0f;
        out_cls[giW] = (float)labels[bj];
        out_reg[giW] = encode_box(aw, gts[bj]);
    }
}

extern "C" void kernel_launch(void* const* d_in, const int* in_sizes, int n_in,
                              void* d_out, int out_size, void* d_ws, size_t ws_size,
                              hipStream_t stream)
{
    const float4* anchors = (const float4*)d_in[0];
    const float4* gts     = (const float4*)d_in[1];
    const int*    labels  = (const int*)d_in[2];
    int n = in_sizes[0] / 4;   // 200000
    int m = in_sizes[1] / 4;   // 128

    float*  out     = (float*)d_out;
    float*  out_cls = out;                       // [n]
    float4* out_reg = (float4*)(out + n);        // [n][4]
    float*  out_pos = out + 5 * (size_t)n;       // [n]
    ull*    ws      = (ull*)d_ws;                // [m][nblocks] packed (val, ~block)

    int nblocks = (n + 127) / 128;               // 1563
    fused_kernel<<<nblocks, 256, 0, stream>>>(anchors, gts, labels, n, m, nblocks,
                                              out_cls, out_reg, out_pos, ws);
    reduce_fixup<<<m, 128, 0, stream>>>(anchors, gts, labels, n, m, nblocks,
                                        out_cls, out_reg, out_pos, ws);
}